// Round 1
// baseline (194.665 us; speedup 1.0000x reference)
//
#include <hip/hip_runtime.h>

#define NN 100000
#define NE 640000
#define DF 128
#define NH 32

// ---------------- GEMM: [xl | xr] = x @ [W1_l | W1_r] ----------------
// Block tile: 64 nodes x 64 outputs, K=128 fully staged in LDS.
// 256 threads: tx = t&15 -> j-quad (j = tx*4), ty = t>>4 -> m-quad (m = ty*4).
__global__ __launch_bounds__(256) void gemm1_kernel(
    const float* __restrict__ x, const float* __restrict__ W1_l,
    const float* __restrict__ W1_r, float* __restrict__ xl, float* __restrict__ xr)
{
    __shared__ float xs[64 * 132];   // [m][k], row stride 132 (pad: 2-way conflicts only)
    __shared__ float wsm[128 * 64];  // [k][j]

    const int t = threadIdx.x;
    const int node0 = blockIdx.x * 64;

    // stage W: cols 0..31 = W1_l, 32..63 = W1_r  (each [128][32] row-major)
    for (int i = t; i < 128 * 64; i += 256) {
        int k = i >> 6, j = i & 63;
        wsm[i] = (j < 32) ? W1_l[k * 32 + j] : W1_r[k * 32 + (j - 32)];
    }
    // stage x rows (coalesced float4 reads)
    const int nvalid = NN - node0;  // may be < 64 for last block
    for (int i = t; i < 64 * 32; i += 256) {  // float4 units: 64 rows x 32 quads
        int r = i >> 5, c4 = i & 31;
        float4 v = make_float4(0.f, 0.f, 0.f, 0.f);
        if (r < nvalid) v = *(const float4*)&x[(size_t)(node0 + r) * DF + c4 * 4];
        *(float4*)&xs[r * 132 + c4 * 4] = v;
    }
    __syncthreads();

    const int tx = t & 15, ty = t >> 4;
    float acc[4][4];
#pragma unroll
    for (int a = 0; a < 4; a++)
#pragma unroll
        for (int b = 0; b < 4; b++) acc[a][b] = 0.f;

    for (int k0 = 0; k0 < 128; k0 += 4) {
        float4 a0 = *(const float4*)&xs[(ty * 4 + 0) * 132 + k0];
        float4 a1 = *(const float4*)&xs[(ty * 4 + 1) * 132 + k0];
        float4 a2 = *(const float4*)&xs[(ty * 4 + 2) * 132 + k0];
        float4 a3 = *(const float4*)&xs[(ty * 4 + 3) * 132 + k0];
        float4 b0 = *(const float4*)&wsm[(k0 + 0) * 64 + tx * 4];
        float4 b1 = *(const float4*)&wsm[(k0 + 1) * 64 + tx * 4];
        float4 b2 = *(const float4*)&wsm[(k0 + 2) * 64 + tx * 4];
        float4 b3 = *(const float4*)&wsm[(k0 + 3) * 64 + tx * 4];
        const float am[4][4] = {{a0.x, a0.y, a0.z, a0.w},
                                {a1.x, a1.y, a1.z, a1.w},
                                {a2.x, a2.y, a2.z, a2.w},
                                {a3.x, a3.y, a3.z, a3.w}};
        const float bm[4][4] = {{b0.x, b0.y, b0.z, b0.w},
                                {b1.x, b1.y, b1.z, b1.w},
                                {b2.x, b2.y, b2.z, b2.w},
                                {b3.x, b3.y, b3.z, b3.w}};
#pragma unroll
        for (int kk = 0; kk < 4; kk++)
#pragma unroll
            for (int mi = 0; mi < 4; mi++)
#pragma unroll
                for (int jq = 0; jq < 4; jq++)
                    acc[mi][jq] = fmaf(am[mi][kk], bm[kk][jq], acc[mi][jq]);
    }

#pragma unroll
    for (int mi = 0; mi < 4; mi++) {
        int node = node0 + ty * 4 + mi;
        if (node < NN) {
            float4 v = make_float4(acc[mi][0], acc[mi][1], acc[mi][2], acc[mi][3]);
            if (tx < 8)
                *(float4*)&xl[(size_t)node * NH + tx * 4] = v;
            else
                *(float4*)&xr[(size_t)node * NH + (tx - 8) * 4] = v;
        }
    }
}

// ---------------- scatter1: agg1[dst] += xl[src], deg[dst] += 1 ----------------
__global__ __launch_bounds__(256) void scatter1_kernel(
    const int* __restrict__ src, const int* __restrict__ dst,
    const float* __restrict__ xl, float* __restrict__ agg1, float* __restrict__ deg)
{
    const int gid = blockIdx.x * 8 + (threadIdx.x >> 5);  // 32-lane group id
    const int f = threadIdx.x & 31;
    const int ngroups = gridDim.x * 8;
    for (int e = gid; e < NE; e += ngroups) {
        int s = src[e], d = dst[e];
        float v = xl[(size_t)s * NH + f];
        atomicAdd(&agg1[(size_t)d * NH + f], v);
        if (f == 0) atomicAdd(&deg[d], 1.0f);
    }
}

// ---------------- h2: h = relu(agg1/deg + xr + b1); h2l = h.W2_l; hrp = h.W2_r ----------------
__global__ __launch_bounds__(256) void h2_kernel(
    const float* __restrict__ agg1, const float* __restrict__ deg,
    const float* __restrict__ xr, const float* __restrict__ b1,
    const float* __restrict__ W2_l, const float* __restrict__ W2_r,
    float* __restrict__ h2l, float* __restrict__ hrp)
{
    const int gid = blockIdx.x * 8 + (threadIdx.x >> 5);
    const int f = threadIdx.x & 31;
    if (gid >= NN) return;
    float dg = fmaxf(deg[gid], 1.0f);
    float h = agg1[(size_t)gid * NH + f] / dg + xr[(size_t)gid * NH + f] + b1[f];
    h = fmaxf(h, 0.0f);
    float sl = h * W2_l[f];
    float sr = h * W2_r[f];
#pragma unroll
    for (int m = 16; m >= 1; m >>= 1) {
        sl += __shfl_xor(sl, m);
        sr += __shfl_xor(sr, m);
    }
    if (f == 0) {
        h2l[gid] = sl;
        hrp[gid] = sr;
    }
}

// ---------------- scatter2: agg2[dst] += h2l[src] ----------------
__global__ __launch_bounds__(256) void scatter2_kernel(
    const int* __restrict__ src, const int* __restrict__ dst,
    const float* __restrict__ h2l, float* __restrict__ agg2)
{
    const int e = blockIdx.x * 256 + threadIdx.x;
    if (e < NE) atomicAdd(&agg2[dst[e]], h2l[src[e]]);
}

// ---------------- final: out = agg2/deg + hrp + b2 ----------------
__global__ __launch_bounds__(256) void final_kernel(
    const float* __restrict__ agg2, const float* __restrict__ deg,
    const float* __restrict__ hrp, const float* __restrict__ b2,
    float* __restrict__ out)
{
    const int i = blockIdx.x * 256 + threadIdx.x;
    if (i < NN) out[i] = agg2[i] / fmaxf(deg[i], 1.0f) + hrp[i] + b2[0];
}

extern "C" void kernel_launch(void* const* d_in, const int* in_sizes, int n_in,
                              void* d_out, int out_size, void* d_ws, size_t ws_size,
                              hipStream_t stream)
{
    const float* x    = (const float*)d_in[0];
    const int*   ei   = (const int*)d_in[1];
    const float* W1_l = (const float*)d_in[2];
    const float* W1_r = (const float*)d_in[3];
    const float* b1   = (const float*)d_in[4];
    const float* W2_l = (const float*)d_in[5];
    const float* W2_r = (const float*)d_in[6];
    const float* b2   = (const float*)d_in[7];
    float* out = (float*)d_out;

    const int* src = ei;
    const int* dst = ei + NE;

    float* xl   = (float*)d_ws;          // N*32
    float* xr   = xl + (size_t)NN * 32;  // N*32
    float* agg1 = xr + (size_t)NN * 32;  // N*32
    float* deg  = agg1 + (size_t)NN * 32; // N
    float* h2l  = deg + NN;              // N
    float* hrp  = h2l + NN;              // N
    float* agg2 = hrp + NN;              // N

    // zero agg1, deg, h2l, hrp, agg2 (contiguous: 36*N floats)
    hipMemsetAsync(agg1, 0, (size_t)NN * 36 * sizeof(float), stream);

    gemm1_kernel<<<(NN + 63) / 64, 256, 0, stream>>>(x, W1_l, W1_r, xl, xr);
    scatter1_kernel<<<20000, 256, 0, stream>>>(src, dst, xl, agg1, deg);
    h2_kernel<<<(NN + 7) / 8, 256, 0, stream>>>(agg1, deg, xr, b1, W2_l, W2_r, h2l, hrp);
    scatter2_kernel<<<(NE + 255) / 256, 256, 0, stream>>>(src, dst, h2l, agg2);
    final_kernel<<<(NN + 255) / 256, 256, 0, stream>>>(agg2, deg, hrp, b2, out);
}

// Round 2
// 151.241 us; speedup vs baseline: 1.2871x; 1.2871x over previous
//
#include <hip/hip_runtime.h>

#define NN 100000
#define NE 640000
#define DF 128
#define NH 32
#define SCAN_CHUNK 1024
#define NB_SCAN ((NN + SCAN_CHUNK - 1) / SCAN_CHUNK)  // 98

// ---------------- GEMM: [xl | xr] = x @ [W1_l | W1_r] ----------------
__global__ __launch_bounds__(256) void gemm1_kernel(
    const float* __restrict__ x, const float* __restrict__ W1_l,
    const float* __restrict__ W1_r, float* __restrict__ xl, float* __restrict__ xr)
{
    __shared__ float xs[64 * 132];
    __shared__ float wsm[128 * 64];

    const int t = threadIdx.x;
    const int node0 = blockIdx.x * 64;

    for (int i = t; i < 128 * 64; i += 256) {
        int k = i >> 6, j = i & 63;
        wsm[i] = (j < 32) ? W1_l[k * 32 + j] : W1_r[k * 32 + (j - 32)];
    }
    const int nvalid = NN - node0;
    for (int i = t; i < 64 * 32; i += 256) {
        int r = i >> 5, c4 = i & 31;
        float4 v = make_float4(0.f, 0.f, 0.f, 0.f);
        if (r < nvalid) v = *(const float4*)&x[(size_t)(node0 + r) * DF + c4 * 4];
        *(float4*)&xs[r * 132 + c4 * 4] = v;
    }
    __syncthreads();

    const int tx = t & 15, ty = t >> 4;
    float acc[4][4];
#pragma unroll
    for (int a = 0; a < 4; a++)
#pragma unroll
        for (int b = 0; b < 4; b++) acc[a][b] = 0.f;

    for (int k0 = 0; k0 < 128; k0 += 4) {
        float4 a0 = *(const float4*)&xs[(ty * 4 + 0) * 132 + k0];
        float4 a1 = *(const float4*)&xs[(ty * 4 + 1) * 132 + k0];
        float4 a2 = *(const float4*)&xs[(ty * 4 + 2) * 132 + k0];
        float4 a3 = *(const float4*)&xs[(ty * 4 + 3) * 132 + k0];
        float4 b0 = *(const float4*)&wsm[(k0 + 0) * 64 + tx * 4];
        float4 b1 = *(const float4*)&wsm[(k0 + 1) * 64 + tx * 4];
        float4 b2 = *(const float4*)&wsm[(k0 + 2) * 64 + tx * 4];
        float4 b3 = *(const float4*)&wsm[(k0 + 3) * 64 + tx * 4];
        const float am[4][4] = {{a0.x, a0.y, a0.z, a0.w},
                                {a1.x, a1.y, a1.z, a1.w},
                                {a2.x, a2.y, a2.z, a2.w},
                                {a3.x, a3.y, a3.z, a3.w}};
        const float bm[4][4] = {{b0.x, b0.y, b0.z, b0.w},
                                {b1.x, b1.y, b1.z, b1.w},
                                {b2.x, b2.y, b2.z, b2.w},
                                {b3.x, b3.y, b3.z, b3.w}};
#pragma unroll
        for (int kk = 0; kk < 4; kk++)
#pragma unroll
            for (int mi = 0; mi < 4; mi++)
#pragma unroll
                for (int jq = 0; jq < 4; jq++)
                    acc[mi][jq] = fmaf(am[mi][kk], bm[kk][jq], acc[mi][jq]);
    }

#pragma unroll
    for (int mi = 0; mi < 4; mi++) {
        int node = node0 + ty * 4 + mi;
        if (node < NN) {
            float4 v = make_float4(acc[mi][0], acc[mi][1], acc[mi][2], acc[mi][3]);
            if (tx < 8)
                *(float4*)&xl[(size_t)node * NH + tx * 4] = v;
            else
                *(float4*)&xr[(size_t)node * NH + (tx - 8) * 4] = v;
        }
    }
}

// ---------------- CSR build ----------------
__global__ __launch_bounds__(256) void hist_kernel(const int* __restrict__ dst,
                                                   int* __restrict__ degi)
{
    int e = blockIdx.x * 256 + threadIdx.x;
    if (e < NE) atomicAdd(&degi[dst[e]], 1);
}

// per-block local exclusive scan over chunks of 1024, block totals to bsum
__global__ __launch_bounds__(256) void scan1_kernel(const int* __restrict__ degi,
                                                    int* __restrict__ rowstart,
                                                    int* __restrict__ bsum)
{
    __shared__ int ls[256];
    const int t = threadIdx.x;
    const int base = blockIdx.x * SCAN_CHUNK;
    const int i0 = base + t * 4;
    int v0 = 0, v1 = 0, v2 = 0, v3 = 0;
    if (i0 + 0 < NN) v0 = degi[i0 + 0];
    if (i0 + 1 < NN) v1 = degi[i0 + 1];
    if (i0 + 2 < NN) v2 = degi[i0 + 2];
    if (i0 + 3 < NN) v3 = degi[i0 + 3];
    int tsum = v0 + v1 + v2 + v3;
    ls[t] = tsum;
    __syncthreads();
    for (int off = 1; off < 256; off <<= 1) {
        int val = (t >= off) ? ls[t - off] : 0;
        __syncthreads();
        ls[t] += val;
        __syncthreads();
    }
    int excl = ls[t] - tsum;
    if (t == 255) bsum[blockIdx.x] = ls[255];
    if (i0 + 0 < NN) rowstart[i0 + 0] = excl;
    if (i0 + 1 < NN) rowstart[i0 + 1] = excl + v0;
    if (i0 + 2 < NN) rowstart[i0 + 2] = excl + v0 + v1;
    if (i0 + 3 < NN) rowstart[i0 + 3] = excl + v0 + v1 + v2;
}

__global__ __launch_bounds__(128) void scan2_kernel(int* __restrict__ bsum,
                                                    int* __restrict__ boff)
{
    __shared__ int ls[128];
    const int t = threadIdx.x;
    int v = (t < NB_SCAN) ? bsum[t] : 0;
    ls[t] = v;
    __syncthreads();
    for (int off = 1; off < 128; off <<= 1) {
        int val = (t >= off) ? ls[t - off] : 0;
        __syncthreads();
        ls[t] += val;
        __syncthreads();
    }
    if (t < NB_SCAN) boff[t] = ls[t] - v;
}

__global__ __launch_bounds__(256) void scan3_kernel(int* __restrict__ rowstart,
                                                    const int* __restrict__ boff,
                                                    int* __restrict__ cursor)
{
    int i = blockIdx.x * 256 + threadIdx.x;
    if (i < NN) {
        int rs = rowstart[i] + boff[i / SCAN_CHUNK];
        rowstart[i] = rs;
        cursor[i] = rs;
    }
}

__global__ __launch_bounds__(256) void fill_kernel(const int* __restrict__ src,
                                                   const int* __restrict__ dst,
                                                   int* __restrict__ cursor,
                                                   int* __restrict__ esrc)
{
    int e = blockIdx.x * 256 + threadIdx.x;
    if (e < NE) {
        int p = atomicAdd(&cursor[dst[e]], 1);
        esrc[p] = src[e];
    }
}

// ---------------- fused layer1 aggregate + relu + layer2 transforms ----------------
// 32 lanes per node. acc = sum xl[src][:]; h = relu(acc/deg + xr + b1);
// h2l = h.W2_l ; hrp = h.W2_r
__global__ __launch_bounds__(256) void agg1_fused_kernel(
    const int* __restrict__ rowstart, const int* __restrict__ degi,
    const int* __restrict__ esrc, const float* __restrict__ xl,
    const float* __restrict__ xr, const float* __restrict__ b1,
    const float* __restrict__ W2_l, const float* __restrict__ W2_r,
    float* __restrict__ h2l, float* __restrict__ hrp)
{
    const int node = blockIdx.x * 8 + (threadIdx.x >> 5);
    const int f = threadIdx.x & 31;
    if (node >= NN) return;
    const int st = rowstart[node];
    const int dg = degi[node];
    float acc0 = 0.f, acc1 = 0.f;
    int j = 0;
    for (; j + 1 < dg; j += 2) {
        int s0 = esrc[st + j];
        int s1 = esrc[st + j + 1];
        acc0 += xl[(size_t)s0 * NH + f];
        acc1 += xl[(size_t)s1 * NH + f];
    }
    if (j < dg) acc0 += xl[(size_t)esrc[st + j] * NH + f];
    float mean = (acc0 + acc1) / fmaxf((float)dg, 1.0f);
    float h = mean + xr[(size_t)node * NH + f] + b1[f];
    h = fmaxf(h, 0.0f);
    float sl = h * W2_l[f];
    float sr = h * W2_r[f];
#pragma unroll
    for (int m = 16; m >= 1; m >>= 1) {
        sl += __shfl_xor(sl, m);
        sr += __shfl_xor(sr, m);
    }
    if (f == 0) {
        h2l[node] = sl;
        hrp[node] = sr;
    }
}

// ---------------- layer2 aggregate + final ----------------
__global__ __launch_bounds__(256) void agg2_final_kernel(
    const int* __restrict__ rowstart, const int* __restrict__ degi,
    const int* __restrict__ esrc, const float* __restrict__ h2l,
    const float* __restrict__ hrp, const float* __restrict__ b2,
    float* __restrict__ out)
{
    int i = blockIdx.x * 256 + threadIdx.x;
    if (i >= NN) return;
    int st = rowstart[i];
    int dg = degi[i];
    float s0 = 0.f, s1 = 0.f;
    int j = 0;
    for (; j + 1 < dg; j += 2) {
        s0 += h2l[esrc[st + j]];
        s1 += h2l[esrc[st + j + 1]];
    }
    if (j < dg) s0 += h2l[esrc[st + j]];
    out[i] = (s0 + s1) / fmaxf((float)dg, 1.0f) + hrp[i] + b2[0];
}

extern "C" void kernel_launch(void* const* d_in, const int* in_sizes, int n_in,
                              void* d_out, int out_size, void* d_ws, size_t ws_size,
                              hipStream_t stream)
{
    const float* x    = (const float*)d_in[0];
    const int*   ei   = (const int*)d_in[1];
    const float* W1_l = (const float*)d_in[2];
    const float* W1_r = (const float*)d_in[3];
    const float* b1   = (const float*)d_in[4];
    const float* W2_l = (const float*)d_in[5];
    const float* W2_r = (const float*)d_in[6];
    const float* b2   = (const float*)d_in[7];
    float* out = (float*)d_out;

    const int* src = ei;
    const int* dst = ei + NE;

    // workspace layout
    float* xl       = (float*)d_ws;                 // NN*32 f32
    float* xr       = xl + (size_t)NN * NH;         // NN*32 f32
    float* h2l      = xr + (size_t)NN * NH;         // NN f32
    float* hrp      = h2l + NN;                     // NN f32
    int*   degi     = (int*)(hrp + NN);             // NN int
    int*   rowstart = degi + NN;                    // NN int
    int*   cursor   = rowstart + NN;                // NN int
    int*   bsum     = cursor + NN;                  // 128 int
    int*   boff     = bsum + 128;                   // 128 int
    int*   esrc     = boff + 128;                   // NE int

    hipMemsetAsync(degi, 0, (size_t)NN * sizeof(int), stream);

    gemm1_kernel<<<(NN + 63) / 64, 256, 0, stream>>>(x, W1_l, W1_r, xl, xr);
    hist_kernel<<<(NE + 255) / 256, 256, 0, stream>>>(dst, degi);
    scan1_kernel<<<NB_SCAN, 256, 0, stream>>>(degi, rowstart, bsum);
    scan2_kernel<<<1, 128, 0, stream>>>(bsum, boff);
    scan3_kernel<<<(NN + 255) / 256, 256, 0, stream>>>(rowstart, boff, cursor);
    fill_kernel<<<(NE + 255) / 256, 256, 0, stream>>>(src, dst, cursor, esrc);
    agg1_fused_kernel<<<(NN + 7) / 8, 256, 0, stream>>>(rowstart, degi, esrc, xl, xr,
                                                        b1, W2_l, W2_r, h2l, hrp);
    agg2_final_kernel<<<(NN + 255) / 256, 256, 0, stream>>>(rowstart, degi, esrc,
                                                            h2l, hrp, b2, out);
}